// Round 12
// baseline (714.157 us; speedup 1.0000x reference)
//
#include <hip/hip_runtime.h>
#include <hip/hip_bf16.h>
#include <hip/hip_fp16.h>
#include <hip/hip_cooperative_groups.h>

namespace cg = cooperative_groups;

#define NEG_SLOPE 0.2f

typedef _Float16 half8 __attribute__((ext_vector_type(8)));
typedef float f32x4 __attribute__((ext_vector_type(4)));

__device__ __forceinline__ float lrelu(float x) { return x >= 0.f ? x : NEG_SLOPE * x; }

__device__ __forceinline__ float4 h4_to_f4(float2 r) {
    __half2 a = *(__half2*)&r.x;
    __half2 b = *(__half2*)&r.y;
    float2 fa = __half22float2(a), fb = __half22float2(b);
    return make_float4(fa.x, fa.y, fb.x, fb.y);
}

__device__ __forceinline__ void fma4(float a, float4 v, float4& acc) {
    acc.x = fmaf(a, v.x, acc.x); acc.y = fmaf(a, v.y, acc.y);
    acc.z = fmaf(a, v.z, acc.z); acc.w = fmaf(a, v.w, acc.w);
}

// ---------------- fused CSR build + weight transpose (cooperative) ----------------
// phases: zero+wt -> hist -> chunk sums -> scan sums -> chunk rescan -> scatter

__global__ __launch_bounds__(256) void k_csr(const int* __restrict__ src,
                                             const int* __restrict__ dst,
                                             int* __restrict__ counts,
                                             int* __restrict__ row_ptr,
                                             int* __restrict__ row_fill,
                                             int* __restrict__ esrc,
                                             int* __restrict__ bsum,
                                             int* __restrict__ boff,
                                             const float* __restrict__ W1,
                                             const float* __restrict__ W2,
                                             __half* __restrict__ W1t,
                                             __half* __restrict__ W2t,
                                             int N, int E) {
    cg::grid_group grid = cg::this_grid();
    __shared__ int lds[256];
    const int nb = gridDim.x;
    const int tid = threadIdx.x;
    const int gtid = blockIdx.x * 256 + tid;
    const int gsz = nb * 256;

    // phase 1: zero counts + weight transposes
    for (int i = gtid; i < N; i += gsz) counts[i] = 0;
    for (int i = gtid; i < 256 * 128; i += gsz) {
        int n = i >> 7, k = i & 127;
        W1t[i] = __float2half(W1[(size_t)k * 256 + n]);
    }
    for (int i = gtid; i < 32 * 256; i += gsz) {
        int n = i >> 8, k = i & 255;
        W2t[i] = __float2half(W2[(size_t)k * 32 + n]);
    }
    grid.sync();

    // phase 2: histogram
    for (int e = gtid; e < E; e += gsz) atomicAdd(&counts[dst[e]], 1);
    grid.sync();

    // phase 3: per-chunk (256 ints) sums
    const int nch = (N + 255) >> 8;        // <= 256
    for (int ch = blockIdx.x; ch < nch; ch += nb) {
        int i = ch * 256 + tid;
        int v = (i < N) ? counts[i] : 0;
        lds[tid] = v;
        __syncthreads();
        for (int off = 128; off; off >>= 1) {
            if (tid < off) lds[tid] += lds[tid + off];
            __syncthreads();
        }
        if (tid == 0) bsum[ch] = lds[0];
        __syncthreads();
    }
    grid.sync();

    // phase 4: exclusive scan of chunk sums (block 0)
    if (blockIdx.x == 0) {
        int v = (tid < nch) ? bsum[tid] : 0;
        lds[tid] = v;
        __syncthreads();
        for (int off = 1; off < 256; off <<= 1) {
            int u = (tid >= off) ? lds[tid - off] : 0;
            __syncthreads();
            lds[tid] += u;
            __syncthreads();
        }
        if (tid < nch) boff[tid] = lds[tid] - v;
        if (tid == nch - 1) row_ptr[N] = lds[tid];
    }
    grid.sync();

    // phase 5: per-chunk rescan -> row_ptr / row_fill
    for (int ch = blockIdx.x; ch < nch; ch += nb) {
        int i = ch * 256 + tid;
        int v = (i < N) ? counts[i] : 0;
        lds[tid] = v;
        __syncthreads();
        for (int off = 1; off < 256; off <<= 1) {
            int u = (tid >= off) ? lds[tid - off] : 0;
            __syncthreads();
            lds[tid] += u;
            __syncthreads();
        }
        int excl = lds[tid] - v;
        if (i < N) {
            int r = boff[ch] + excl;
            row_ptr[i] = r;
            row_fill[i] = r;
        }
        __syncthreads();
    }
    grid.sync();

    // phase 6: scatter edges into CSR order
    for (int e = gtid; e < E; e += gsz) {
        int p = atomicAdd(&row_fill[dst[e]], 1);
        esrc[p] = src[e];
    }
}

// ---------------- GEMM1 (MFMA fp16): h1 = x @ W1, fused att dots ----------------

__global__ __launch_bounds__(256, 2) void k_gemm1(const float* __restrict__ x,
                                                  const __half* __restrict__ Wt,
                                                  const float* __restrict__ att_src,
                                                  const float* __restrict__ att_dst,
                                                  __half* __restrict__ h,
                                                  float* __restrict__ a_s,
                                                  float* __restrict__ a_d, int M) {
    __shared__ __align__(16) __half Xs[128 * 128];   // [row][k], XOR-swizzled 16B chunks
    __shared__ __align__(16) __half Ws[128 * 128];   // [perm-slot][k], XOR-swizzled
    const int tid = threadIdx.x;
    const int row0 = blockIdx.x * 128;
    const int by = blockIdx.y;
    const int col0 = by * 128;

    for (int t = 0; t < 8; ++t) {
        int c = tid + t * 256;
        int row = c >> 4, ch = c & 15;
        int r = row0 + row;
        float4 va = make_float4(0.f, 0.f, 0.f, 0.f), vb = va;
        if (r < M) {
            va = *(const float4*)&x[(size_t)r * 128 + ch * 8];
            vb = *(const float4*)&x[(size_t)r * 128 + ch * 8 + 4];
        }
        half8 hv;
        hv[0] = (_Float16)va.x; hv[1] = (_Float16)va.y;
        hv[2] = (_Float16)va.z; hv[3] = (_Float16)va.w;
        hv[4] = (_Float16)vb.x; hv[5] = (_Float16)vb.y;
        hv[6] = (_Float16)vb.z; hv[7] = (_Float16)vb.w;
        *(half8*)((char*)Xs + row * 256 + ((ch * 16) ^ ((row & 7) << 4))) = hv;
    }
    for (int t = 0; t < 8; ++t) {
        int c = tid + t * 256;
        int n = c >> 4, ch = c & 15;
        int p = ((n & 7) << 4) | (n >> 3);
        float4 v = *(const float4*)&Wt[(size_t)(col0 + n) * 128 + ch * 8];
        *(float4*)((char*)Ws + p * 256 + ((ch * 16) ^ ((p & 7) << 4))) = v;
    }
    __syncthreads();

    const int w = tid >> 6, lane = tid & 63;
    const int col_l = lane & 15, kgrp = lane >> 4;
    const int sw = (col_l & 7) << 4;
    const int arow0 = w * 32 + col_l;
    const int arow1 = arow0 + 16;

    f32x4 acc[2][8];
#pragma unroll
    for (int mt = 0; mt < 2; ++mt)
#pragma unroll
        for (int nt = 0; nt < 8; ++nt) acc[mt][nt] = (f32x4){0.f, 0.f, 0.f, 0.f};

#pragma unroll
    for (int ks = 0; ks < 4; ++ks) {
        int kchunk = (ks * 4 + kgrp) * 16;
        half8 av0 = *(const half8*)((const char*)Xs + arow0 * 256 + (kchunk ^ sw));
        half8 av1 = *(const half8*)((const char*)Xs + arow1 * 256 + (kchunk ^ sw));
#pragma unroll
        for (int nt = 0; nt < 8; ++nt) {
            half8 bv = *(const half8*)((const char*)Ws + (nt * 16 + col_l) * 256 + (kchunk ^ sw));
            acc[0][nt] = __builtin_amdgcn_mfma_f32_16x16x32_f16(av0, bv, acc[0][nt], 0, 0, 0);
            acc[1][nt] = __builtin_amdgcn_mfma_f32_16x16x32_f16(av1, bv, acc[1][nt], 0, 0, 0);
        }
    }

    float asv[8], adv[8];
    *(float4*)&asv[0] = *(const float4*)&att_src[col0 + col_l * 8];
    *(float4*)&asv[4] = *(const float4*)&att_src[col0 + col_l * 8 + 4];
    *(float4*)&adv[0] = *(const float4*)&att_dst[col0 + col_l * 8];
    *(float4*)&adv[4] = *(const float4*)&att_dst[col0 + col_l * 8 + 4];

#pragma unroll
    for (int mt = 0; mt < 2; ++mt) {
        const int rbase = row0 + w * 32 + mt * 16 + kgrp * 4;
#pragma unroll
        for (int reg = 0; reg < 4; ++reg) {
            int gr = rbase + reg;
            if (gr < M) {
                half8 hv;
#pragma unroll
                for (int nt = 0; nt < 8; ++nt) hv[nt] = (_Float16)acc[mt][nt][reg];
                *(half8*)&h[(size_t)gr * 256 + col0 + col_l * 8] = hv;
            }
            float s_ = 0.f, d_ = 0.f;
#pragma unroll
            for (int nt = 0; nt < 8; ++nt) {
                s_ = fmaf(acc[mt][nt][reg], asv[nt], s_);
                d_ = fmaf(acc[mt][nt][reg], adv[nt], d_);
            }
#pragma unroll
            for (int off = 1; off < 8; off <<= 1) {
                s_ += __shfl_xor(s_, off);
                d_ += __shfl_xor(d_, off);
            }
            if ((col_l & 7) == 0 && gr < M) {
                int head = by * 2 + (col_l >> 3);
                a_s[(size_t)gr * 4 + head] = s_;
                a_d[(size_t)gr * 4 + head] = d_;
            }
        }
    }
}

// ---------------- agg layer 1 (fused softmax): wave-per-node ----------------

__global__ __launch_bounds__(256) void k_agg1(const __half* __restrict__ h1,
                                              const int* __restrict__ row_ptr,
                                              const int* __restrict__ esrc,
                                              const float* __restrict__ asrc,
                                              const float* __restrict__ adst,
                                              const float* __restrict__ b1,
                                              __half* __restrict__ y1, int N) {
    __shared__ int ss[4][64];
    __shared__ float sa[4][64 * 4];
    int tid = threadIdx.x;
    int wv = tid >> 6, lane = tid & 63;
    int n = blockIdx.x * 4 + wv;
    if (n >= N) return;
    int head = lane >> 4;
    int e0 = row_ptr[n], e1 = row_ptr[n + 1];
    int deg = e1 - e0;
    const float4 ad = *(const float4*)&adst[(size_t)n * 4];
    float4 acc = make_float4(0.f, 0.f, 0.f, 0.f);
    float4 asum = make_float4(0.f, 0.f, 0.f, 0.f);

    if (deg <= 64) {
        float4 l = make_float4(-3e38f, -3e38f, -3e38f, -3e38f);
        if (lane < deg) {
            int s = esrc[e0 + lane];
            ss[wv][lane] = s;
            float4 as = *(const float4*)&asrc[(size_t)s * 4];
            l.x = lrelu(as.x + ad.x); l.y = lrelu(as.y + ad.y);
            l.z = lrelu(as.z + ad.z); l.w = lrelu(as.w + ad.w);
        }
        float4 m = l;
#pragma unroll
        for (int off = 1; off < 64; off <<= 1) {
            m.x = fmaxf(m.x, __shfl_xor(m.x, off));
            m.y = fmaxf(m.y, __shfl_xor(m.y, off));
            m.z = fmaxf(m.z, __shfl_xor(m.z, off));
            m.w = fmaxf(m.w, __shfl_xor(m.w, off));
        }
        float4 a = make_float4(0.f, 0.f, 0.f, 0.f);
        if (lane < deg) {
            a.x = __expf(l.x - m.x); a.y = __expf(l.y - m.y);
            a.z = __expf(l.z - m.z); a.w = __expf(l.w - m.w);
            *(float4*)&sa[wv][lane * 4] = a;
        }
        asum = a;
        int i = 0;
        for (; i + 3 < deg; i += 4) {
            int s0 = ss[wv][i], s1 = ss[wv][i + 1], s2 = ss[wv][i + 2], s3 = ss[wv][i + 3];
            float a0 = sa[wv][i * 4 + head],       a1 = sa[wv][(i + 1) * 4 + head];
            float a2 = sa[wv][(i + 2) * 4 + head], a3 = sa[wv][(i + 3) * 4 + head];
            float2 r0 = *(const float2*)&h1[(size_t)s0 * 256 + lane * 4];
            float2 r1 = *(const float2*)&h1[(size_t)s1 * 256 + lane * 4];
            float2 r2 = *(const float2*)&h1[(size_t)s2 * 256 + lane * 4];
            float2 r3 = *(const float2*)&h1[(size_t)s3 * 256 + lane * 4];
            fma4(a0, h4_to_f4(r0), acc);
            fma4(a1, h4_to_f4(r1), acc);
            fma4(a2, h4_to_f4(r2), acc);
            fma4(a3, h4_to_f4(r3), acc);
        }
        for (; i < deg; ++i) {
            int s0 = ss[wv][i];
            float a0 = sa[wv][i * 4 + head];
            float2 r0 = *(const float2*)&h1[(size_t)s0 * 256 + lane * 4];
            fma4(a0, h4_to_f4(r0), acc);
        }
    } else {
        float4 m = make_float4(-3e38f, -3e38f, -3e38f, -3e38f);
        for (int p0 = e0; p0 < e1; p0 += 64) {
            int e = p0 + lane;
            if (e < e1) {
                int s = esrc[e];
                float4 as = *(const float4*)&asrc[(size_t)s * 4];
                m.x = fmaxf(m.x, lrelu(as.x + ad.x));
                m.y = fmaxf(m.y, lrelu(as.y + ad.y));
                m.z = fmaxf(m.z, lrelu(as.z + ad.z));
                m.w = fmaxf(m.w, lrelu(as.w + ad.w));
            }
        }
#pragma unroll
        for (int off = 1; off < 64; off <<= 1) {
            m.x = fmaxf(m.x, __shfl_xor(m.x, off));
            m.y = fmaxf(m.y, __shfl_xor(m.y, off));
            m.z = fmaxf(m.z, __shfl_xor(m.z, off));
            m.w = fmaxf(m.w, __shfl_xor(m.w, off));
        }
        for (int p0 = e0; p0 < e1; p0 += 64) {
            int cnt = min(64, e1 - p0);
            if (lane < cnt) {
                int s = esrc[p0 + lane];
                ss[wv][lane] = s;
                float4 as = *(const float4*)&asrc[(size_t)s * 4];
                float4 a;
                a.x = __expf(lrelu(as.x + ad.x) - m.x);
                a.y = __expf(lrelu(as.y + ad.y) - m.y);
                a.z = __expf(lrelu(as.z + ad.z) - m.z);
                a.w = __expf(lrelu(as.w + ad.w) - m.w);
                *(float4*)&sa[wv][lane * 4] = a;
                asum.x += a.x; asum.y += a.y; asum.z += a.z; asum.w += a.w;
            }
            int i = 0;
            for (; i + 3 < cnt; i += 4) {
                int s0 = ss[wv][i], s1 = ss[wv][i + 1], s2 = ss[wv][i + 2], s3 = ss[wv][i + 3];
                float a0 = sa[wv][i * 4 + head],       a1 = sa[wv][(i + 1) * 4 + head];
                float a2 = sa[wv][(i + 2) * 4 + head], a3 = sa[wv][(i + 3) * 4 + head];
                float2 r0 = *(const float2*)&h1[(size_t)s0 * 256 + lane * 4];
                float2 r1 = *(const float2*)&h1[(size_t)s1 * 256 + lane * 4];
                float2 r2 = *(const float2*)&h1[(size_t)s2 * 256 + lane * 4];
                float2 r3 = *(const float2*)&h1[(size_t)s3 * 256 + lane * 4];
                fma4(a0, h4_to_f4(r0), acc);
                fma4(a1, h4_to_f4(r1), acc);
                fma4(a2, h4_to_f4(r2), acc);
                fma4(a3, h4_to_f4(r3), acc);
            }
            for (; i < cnt; ++i) {
                int s0 = ss[wv][i];
                float a0 = sa[wv][i * 4 + head];
                float2 r0 = *(const float2*)&h1[(size_t)s0 * 256 + lane * 4];
                fma4(a0, h4_to_f4(r0), acc);
            }
        }
    }

#pragma unroll
    for (int off = 1; off < 64; off <<= 1) {
        asum.x += __shfl_xor(asum.x, off);
        asum.y += __shfl_xor(asum.y, off);
        asum.z += __shfl_xor(asum.z, off);
        asum.w += __shfl_xor(asum.w, off);
    }
    float ssum = (head == 0) ? asum.x : (head == 1) ? asum.y : (head == 2) ? asum.z : asum.w;
    float inv = 1.f / (ssum + 1e-16f);
    float4 bb = *(const float4*)&b1[lane * 4];
    float4 v;
    v.x = acc.x * inv + bb.x; v.y = acc.y * inv + bb.y;
    v.z = acc.z * inv + bb.z; v.w = acc.w * inv + bb.w;
    v.x = (v.x > 0.f) ? v.x : (__expf(v.x) - 1.f);
    v.y = (v.y > 0.f) ? v.y : (__expf(v.y) - 1.f);
    v.z = (v.z > 0.f) ? v.z : (__expf(v.z) - 1.f);
    v.w = (v.w > 0.f) ? v.w : (__expf(v.w) - 1.f);
    __half2 h01 = __floats2half2_rn(v.x, v.y);
    __half2 h23 = __floats2half2_rn(v.z, v.w);
    float2 st;
    *(__half2*)&st.x = h01;
    *(__half2*)&st.y = h23;
    *(float2*)&y1[(size_t)n * 256 + lane * 4] = st;
}

// ---------------- GEMM2 (MFMA fp16): h2 = y1 @ W2, fused att dots ----------------

__global__ __launch_bounds__(256, 3) void k_gemm2(const __half* __restrict__ y1,
                                                  const __half* __restrict__ W2t,
                                                  const float* __restrict__ att_src,
                                                  const float* __restrict__ att_dst,
                                                  __half* __restrict__ h2,
                                                  float* __restrict__ a_s,
                                                  float* __restrict__ a_d, int M) {
    __shared__ __align__(16) __half Ys[64 * 256];
    __shared__ __align__(16) __half Ws[32 * 256];
    const int tid = threadIdx.x;
    const int row0 = blockIdx.x * 64;

    for (int t = 0; t < 8; ++t) {
        int c = tid + t * 256;
        int row = c >> 5, ch = c & 31;
        int r = row0 + row;
        float4 v = make_float4(0.f, 0.f, 0.f, 0.f);
        if (r < M) v = *(const float4*)&y1[(size_t)r * 256 + ch * 8];
        *(float4*)((char*)Ys + row * 512 + ((ch * 16) ^ ((row & 7) << 4))) = v;
    }
    for (int t = 0; t < 4; ++t) {
        int c = tid + t * 256;
        int n = c >> 5, ch = c & 31;
        int p = ((n & 1) << 4) | (n >> 1);
        float4 v = *(const float4*)&W2t[(size_t)n * 256 + ch * 8];
        *(float4*)((char*)Ws + p * 512 + ((ch * 16) ^ ((p & 7) << 4))) = v;
    }
    __syncthreads();

    const int w = tid >> 6, lane = tid & 63;
    const int col_l = lane & 15, kgrp = lane >> 4;
    const int arow = w * 16 + col_l;
    const int sw = (col_l & 7) << 4;

    f32x4 acc[2];
    acc[0] = (f32x4){0.f, 0.f, 0.f, 0.f};
    acc[1] = (f32x4){0.f, 0.f, 0.f, 0.f};

#pragma unroll
    for (int ks = 0; ks < 8; ++ks) {
        int kchunk = (ks * 4 + kgrp) * 16;
        half8 av = *(const half8*)((const char*)Ys + arow * 512 + (kchunk ^ sw));
#pragma unroll
        for (int nt = 0; nt < 2; ++nt) {
            half8 bv = *(const half8*)((const char*)Ws + (nt * 16 + col_l) * 512 + (kchunk ^ sw));
            acc[nt] = __builtin_amdgcn_mfma_f32_16x16x32_f16(av, bv, acc[nt], 0, 0, 0);
        }
    }

    float asv[2], adv[2];
    asv[0] = att_src[col_l * 2]; asv[1] = att_src[col_l * 2 + 1];
    adv[0] = att_dst[col_l * 2]; adv[1] = att_dst[col_l * 2 + 1];
    const int rbase = row0 + w * 16 + kgrp * 4;
#pragma unroll
    for (int reg = 0; reg < 4; ++reg) {
        int gr = rbase + reg;
        if (gr < M) {
            __half2 hv = __floats2half2_rn(acc[0][reg], acc[1][reg]);
            *(__half2*)&h2[(size_t)gr * 32 + col_l * 2] = hv;
        }
        float s_ = fmaf(acc[0][reg], asv[0], acc[1][reg] * asv[1]);
        float d_ = fmaf(acc[0][reg], adv[0], acc[1][reg] * adv[1]);
#pragma unroll
        for (int off = 1; off < 16; off <<= 1) {
            s_ += __shfl_xor(s_, off);
            d_ += __shfl_xor(d_, off);
        }
        if (col_l == 0 && gr < M) { a_s[gr] = s_; a_d[gr] = d_; }
    }
}

// ---------------- agg layer 2 (fused softmax): wave-per-node ----------------

__global__ __launch_bounds__(256) void k_agg2(const __half* __restrict__ h2,
                                              const int* __restrict__ row_ptr,
                                              const int* __restrict__ esrc,
                                              const float* __restrict__ asrc,
                                              const float* __restrict__ adst,
                                              const float* __restrict__ b2,
                                              float* __restrict__ out, int N) {
    __shared__ int ss[4][64];
    __shared__ float sa[4][64];
    int tid = threadIdx.x;
    int wv = tid >> 6, lane = tid & 63;
    int n = blockIdx.x * 4 + wv;
    if (n >= N) return;
    int grp = lane >> 4, cl = lane & 15;
    int e0 = row_ptr[n], e1 = row_ptr[n + 1];
    int deg = e1 - e0;
    float ad = adst[n];
    float2 acc = make_float2(0.f, 0.f);
    float asum = 0.f;

    auto gather = [&](int cnt) {
        int i = 0;
        for (; i + 7 < cnt; i += 8) {
            int ea = i + grp, eb = i + 4 + grp;
            int s0 = ss[wv][ea], s1 = ss[wv][eb];
            float a0 = sa[wv][ea], a1 = sa[wv][eb];
            __half2 v0 = *(const __half2*)&h2[(size_t)s0 * 32 + cl * 2];
            __half2 v1 = *(const __half2*)&h2[(size_t)s1 * 32 + cl * 2];
            float2 f0 = __half22float2(v0), f1 = __half22float2(v1);
            acc.x = fmaf(a0, f0.x, acc.x); acc.y = fmaf(a0, f0.y, acc.y);
            acc.x = fmaf(a1, f1.x, acc.x); acc.y = fmaf(a1, f1.y, acc.y);
        }
        for (; i < cnt; i += 4) {
            int e = i + grp;
            if (e < cnt) {
                int s0 = ss[wv][e];
                float a0 = sa[wv][e];
                __half2 v0 = *(const __half2*)&h2[(size_t)s0 * 32 + cl * 2];
                float2 f0 = __half22float2(v0);
                acc.x = fmaf(a0, f0.x, acc.x); acc.y = fmaf(a0, f0.y, acc.y);
            }
        }
    };

    if (deg <= 64) {
        float l = -3e38f;
        if (lane < deg) {
            int s = esrc[e0 + lane];
            ss[wv][lane] = s;
            l = lrelu(asrc[s] + ad);
        }
        float m = l;
#pragma unroll
        for (int off = 1; off < 64; off <<= 1) m = fmaxf(m, __shfl_xor(m, off));
        float a = 0.f;
        if (lane < deg) {
            a = __expf(l - m);
            sa[wv][lane] = a;
        }
        asum = a;
        gather(deg);
    } else {
        float m = -3e38f;
        for (int p0 = e0; p0 < e1; p0 += 64) {
            int e = p0 + lane;
            if (e < e1) m = fmaxf(m, lrelu(asrc[esrc[e]] + ad));
        }
#pragma unroll
        for (int off = 1; off < 64; off <<= 1) m = fmaxf(m, __shfl_xor(m, off));
        for (int p0 = e0; p0 < e1; p0 += 64) {
            int cnt = min(64, e1 - p0);
            if (lane < cnt) {
                int s = esrc[p0 + lane];
                ss[wv][lane] = s;
                float a = __expf(lrelu(asrc[s] + ad) - m);
                sa[wv][lane] = a;
                asum += a;
            }
            gather(cnt);
        }
    }

    acc.x += __shfl_xor(acc.x, 16); acc.y += __shfl_xor(acc.y, 16);
    acc.x += __shfl_xor(acc.x, 32); acc.y += __shfl_xor(acc.y, 32);
#pragma unroll
    for (int off = 1; off < 64; off <<= 1) asum += __shfl_xor(asum, off);
    if (grp == 0) {
        float inv = 1.f / (asum + 1e-16f);
        float2 o;
        o.x = acc.x * inv + b2[cl * 2];
        o.y = acc.y * inv + b2[cl * 2 + 1];
        *(float2*)&out[(size_t)n * 32 + cl * 2] = o;
    }
}

// ---------------- launcher ----------------

extern "C" void kernel_launch(void* const* d_in, const int* in_sizes, int n_in,
                              void* d_out, int out_size, void* d_ws, size_t ws_size,
                              hipStream_t stream) {
    const float* x   = (const float*)d_in[0];
    const int*   ei  = (const int*)d_in[1];
    const float* W1  = (const float*)d_in[2];
    const float* as1 = (const float*)d_in[3];
    const float* ad1 = (const float*)d_in[4];
    const float* b1  = (const float*)d_in[5];
    const float* W2  = (const float*)d_in[6];
    const float* as2 = (const float*)d_in[7];
    const float* ad2 = (const float*)d_in[8];
    const float* b2  = (const float*)d_in[9];
    float* out = (float*)d_out;

    int N = in_sizes[0] / 128;   // 50000
    int E = in_sizes[1] / 2;     // 800000
    const int* src = ei;
    const int* dstp = ei + E;

    char* ws = (char*)d_ws;
    size_t off = 0;
    auto alloc = [&](size_t nbytes) {
        void* p = ws + off;
        off += (nbytes + 255) & ~(size_t)255;
        return p;
    };
    int* counts    = (int*)alloc((size_t)N * 4);
    int* row_ptr   = (int*)alloc((size_t)(N + 1) * 4);
    int* row_fill  = (int*)alloc((size_t)N * 4);
    int* esrc      = (int*)alloc((size_t)E * 4);
    __half* h1     = (__half*)alloc((size_t)N * 256 * 2);
    __half* y1     = (__half*)alloc((size_t)N * 256 * 2);
    __half* h2     = (__half*)alloc((size_t)N * 32 * 2);
    float* a_s1    = (float*)alloc((size_t)N * 4 * 4);
    float* a_d1    = (float*)alloc((size_t)N * 4 * 4);
    float* a_s2    = (float*)alloc((size_t)N * 4);
    float* a_d2    = (float*)alloc((size_t)N * 4);
    int* bsum      = (int*)alloc(256 * 4);
    int* boff      = (int*)alloc(256 * 4);
    __half* Wt     = (__half*)alloc((size_t)256 * 128 * 2);
    __half* W2t    = (__half*)alloc((size_t)32 * 256 * 2);

    void* csr_args[] = {(void*)&src, (void*)&dstp, (void*)&counts, (void*)&row_ptr,
                        (void*)&row_fill, (void*)&esrc, (void*)&bsum, (void*)&boff,
                        (void*)&W1, (void*)&W2, (void*)&Wt, (void*)&W2t,
                        (void*)&N, (void*)&E};
    hipLaunchCooperativeKernel((void*)k_csr, dim3(1024), dim3(256), csr_args, 0, stream);

    k_gemm1<<<dim3((N + 127) / 128, 2), 256, 0, stream>>>(x, Wt, as1, ad1, h1, a_s1, a_d1, N);
    k_agg1<<<(N + 3) / 4, 256, 0, stream>>>(h1, row_ptr, esrc, a_s1, a_d1, b1, y1, N);

    k_gemm2<<<(N + 63) / 64, 256, 0, stream>>>(y1, W2t, as2, ad2, h2, a_s2, a_d2, N);
    k_agg2<<<(N + 3) / 4, 256, 0, stream>>>(h2, row_ptr, esrc, a_s2, a_d2, b2, out, N);
}

// Round 13
// 222.301 us; speedup vs baseline: 3.2126x; 3.2126x over previous
//
#include <hip/hip_runtime.h>
#include <hip/hip_bf16.h>
#include <hip/hip_fp16.h>

#define NEG_SLOPE 0.2f

typedef _Float16 half8 __attribute__((ext_vector_type(8)));
typedef float f32x4 __attribute__((ext_vector_type(4)));

__device__ __forceinline__ float lrelu(float x) { return x >= 0.f ? x : NEG_SLOPE * x; }

// ---------------- CSR construction ----------------

__global__ void k_hist(const int* __restrict__ dst, int* __restrict__ counts, int E) {
    int e = blockIdx.x * 256 + threadIdx.x;
    if (e < E) atomicAdd(&counts[dst[e]], 1);
}

__global__ __launch_bounds__(256) void k_scan1(const int* __restrict__ counts,
                                               int* __restrict__ bsum, int N) {
    __shared__ int wsum[4];
    int b = blockIdx.x, t = threadIdx.x;
    int i0 = b * 1024 + t * 4;
    int s = 0;
    if (i0 < N) { int4 v = *(const int4*)&counts[i0]; s = v.x + v.y + v.z + v.w; }
#pragma unroll
    for (int off = 32; off; off >>= 1) s += __shfl_down(s, off);
    if ((t & 63) == 0) wsum[t >> 6] = s;
    __syncthreads();
    if (t == 0) bsum[b] = wsum[0] + wsum[1] + wsum[2] + wsum[3];
}

__global__ void k_scan2(const int* __restrict__ bsum, int* __restrict__ boff,
                        int* __restrict__ row_ptrN, int nb) {
    int t = threadIdx.x;  // 64 threads, nb <= 64
    int v = (t < nb) ? bsum[t] : 0;
    int incl = v;
#pragma unroll
    for (int off = 1; off < 64; off <<= 1) {
        int u = __shfl_up(incl, off);
        if (t >= off) incl += u;
    }
    if (t < nb) boff[t] = incl - v;
    if (t == nb - 1) *row_ptrN = incl;
}

__global__ __launch_bounds__(256) void k_scan3(const int* __restrict__ counts,
                                               const int* __restrict__ boff,
                                               int* __restrict__ row_ptr,
                                               int* __restrict__ row_fill, int N) {
    __shared__ int lds[256];
    int b = blockIdx.x, t = threadIdx.x;
    int i0 = b * 1024 + t * 4;
    int4 v = make_int4(0, 0, 0, 0);
    if (i0 < N) v = *(const int4*)&counts[i0];
    int tot = v.x + v.y + v.z + v.w;
    lds[t] = tot;
    __syncthreads();
    for (int off = 1; off < 256; off <<= 1) {
        int u = (t >= off) ? lds[t - off] : 0;
        __syncthreads();
        lds[t] += u;
        __syncthreads();
    }
    int excl = lds[t] - tot;
    int run = boff[b] + excl;
    if (i0 < N) {
        row_ptr[i0] = run;     row_fill[i0] = run;     run += v.x;
        row_ptr[i0 + 1] = run; row_fill[i0 + 1] = run; run += v.y;
        row_ptr[i0 + 2] = run; row_fill[i0 + 2] = run; run += v.z;
        row_ptr[i0 + 3] = run; row_fill[i0 + 3] = run;
    }
}

__global__ void k_scatter(const int* __restrict__ src, const int* __restrict__ dst,
                          int* __restrict__ row_fill, int* __restrict__ esrc, int E) {
    int e = blockIdx.x * 256 + threadIdx.x;
    if (e < E) {
        int p = atomicAdd(&row_fill[dst[e]], 1);
        esrc[p] = src[e];
    }
}

// ---------------- weight transposes to fp16 (merged) ----------------

__global__ __launch_bounds__(256) void k_wt(const float* __restrict__ W1,
                                            const float* __restrict__ W2,
                                            __half* __restrict__ W1t,
                                            __half* __restrict__ W2t) {
    int b = blockIdx.x, k = threadIdx.x;
    if (b < 256) {
        if (k < 128) W1t[b * 128 + k] = __float2half(W1[(size_t)k * 256 + b]);
    } else {
        int n = b - 256;   // 0..31
        W2t[n * 256 + k] = __float2half(W2[(size_t)k * 32 + n]);
    }
}

// ---------------- GEMM1 (MFMA fp16): h1 = x @ W1, fused att dots ----------------

__global__ __launch_bounds__(256, 2) void k_gemm1(const float* __restrict__ x,
                                                  const __half* __restrict__ Wt,
                                                  const float* __restrict__ att_src,
                                                  const float* __restrict__ att_dst,
                                                  __half* __restrict__ h,
                                                  float* __restrict__ a_s,
                                                  float* __restrict__ a_d, int M) {
    __shared__ __align__(16) __half Xs[128 * 128];   // [row][k], XOR-swizzled 16B chunks
    __shared__ __align__(16) __half Ws[128 * 128];   // [perm-slot][k], XOR-swizzled
    const int tid = threadIdx.x;
    const int row0 = blockIdx.x * 128;
    const int by = blockIdx.y;
    const int col0 = by * 128;

    for (int t = 0; t < 8; ++t) {
        int c = tid + t * 256;
        int row = c >> 4, ch = c & 15;
        int r = row0 + row;
        float4 va = make_float4(0.f, 0.f, 0.f, 0.f), vb = va;
        if (r < M) {
            va = *(const float4*)&x[(size_t)r * 128 + ch * 8];
            vb = *(const float4*)&x[(size_t)r * 128 + ch * 8 + 4];
        }
        half8 hv;
        hv[0] = (_Float16)va.x; hv[1] = (_Float16)va.y;
        hv[2] = (_Float16)va.z; hv[3] = (_Float16)va.w;
        hv[4] = (_Float16)vb.x; hv[5] = (_Float16)vb.y;
        hv[6] = (_Float16)vb.z; hv[7] = (_Float16)vb.w;
        *(half8*)((char*)Xs + row * 256 + ((ch * 16) ^ ((row & 7) << 4))) = hv;
    }
    for (int t = 0; t < 8; ++t) {
        int c = tid + t * 256;
        int n = c >> 4, ch = c & 15;
        int p = ((n & 7) << 4) | (n >> 3);
        float4 v = *(const float4*)&Wt[(size_t)(col0 + n) * 128 + ch * 8];
        *(float4*)((char*)Ws + p * 256 + ((ch * 16) ^ ((p & 7) << 4))) = v;
    }
    __syncthreads();

    const int w = tid >> 6, lane = tid & 63;
    const int col_l = lane & 15, kgrp = lane >> 4;
    const int sw = (col_l & 7) << 4;
    const int arow0 = w * 32 + col_l;
    const int arow1 = arow0 + 16;

    f32x4 acc[2][8];
#pragma unroll
    for (int mt = 0; mt < 2; ++mt)
#pragma unroll
        for (int nt = 0; nt < 8; ++nt) acc[mt][nt] = (f32x4){0.f, 0.f, 0.f, 0.f};

#pragma unroll
    for (int ks = 0; ks < 4; ++ks) {
        int kchunk = (ks * 4 + kgrp) * 16;
        half8 av0 = *(const half8*)((const char*)Xs + arow0 * 256 + (kchunk ^ sw));
        half8 av1 = *(const half8*)((const char*)Xs + arow1 * 256 + (kchunk ^ sw));
#pragma unroll
        for (int nt = 0; nt < 8; ++nt) {
            half8 bv = *(const half8*)((const char*)Ws + (nt * 16 + col_l) * 256 + (kchunk ^ sw));
            acc[0][nt] = __builtin_amdgcn_mfma_f32_16x16x32_f16(av0, bv, acc[0][nt], 0, 0, 0);
            acc[1][nt] = __builtin_amdgcn_mfma_f32_16x16x32_f16(av1, bv, acc[1][nt], 0, 0, 0);
        }
    }

    float asv[8], adv[8];
    *(float4*)&asv[0] = *(const float4*)&att_src[col0 + col_l * 8];
    *(float4*)&asv[4] = *(const float4*)&att_src[col0 + col_l * 8 + 4];
    *(float4*)&adv[0] = *(const float4*)&att_dst[col0 + col_l * 8];
    *(float4*)&adv[4] = *(const float4*)&att_dst[col0 + col_l * 8 + 4];

#pragma unroll
    for (int mt = 0; mt < 2; ++mt) {
        const int rbase = row0 + w * 32 + mt * 16 + kgrp * 4;
#pragma unroll
        for (int reg = 0; reg < 4; ++reg) {
            int gr = rbase + reg;
            if (gr < M) {
                half8 hv;
#pragma unroll
                for (int nt = 0; nt < 8; ++nt) hv[nt] = (_Float16)acc[mt][nt][reg];
                *(half8*)&h[(size_t)gr * 256 + col0 + col_l * 8] = hv;
            }
            float s_ = 0.f, d_ = 0.f;
#pragma unroll
            for (int nt = 0; nt < 8; ++nt) {
                s_ = fmaf(acc[mt][nt][reg], asv[nt], s_);
                d_ = fmaf(acc[mt][nt][reg], adv[nt], d_);
            }
#pragma unroll
            for (int off = 1; off < 8; off <<= 1) {
                s_ += __shfl_xor(s_, off);
                d_ += __shfl_xor(d_, off);
            }
            if ((col_l & 7) == 0 && gr < M) {
                int head = by * 2 + (col_l >> 3);
                a_s[(size_t)gr * 4 + head] = s_;
                a_d[(size_t)gr * 4 + head] = d_;
            }
        }
    }
}

// ---------------- agg layer 1 (fused softmax): wave-per-node, 2 rows/step x half8 ----------------

__global__ __launch_bounds__(256) void k_agg1(const __half* __restrict__ h1,
                                              const int* __restrict__ row_ptr,
                                              const int* __restrict__ esrc,
                                              const float* __restrict__ asrc,
                                              const float* __restrict__ adst,
                                              const float* __restrict__ b1,
                                              __half* __restrict__ y1, int N) {
    __shared__ int ss[4][64];
    __shared__ float sa[4][64 * 4];
    int tid = threadIdx.x;
    int wv = tid >> 6, lane = tid & 63;
    int n = blockIdx.x * 4 + wv;
    if (n >= N) return;
    int g = lane >> 5;            // edge subgroup 0/1
    int li = lane & 31;           // channel-block: channels li*8..li*8+7
    int head = li >> 3;           // 64-ch head of this lane's channels
    int e0 = row_ptr[n], e1 = row_ptr[n + 1];
    int deg = e1 - e0;
    const float4 ad = *(const float4*)&adst[(size_t)n * 4];
    float acc[8] = {};
    float4 asum = make_float4(0.f, 0.f, 0.f, 0.f);

    auto gath1 = [&](int e) {   // one edge for this subgroup's lanes
        int s = ss[wv][e];
        float a = sa[wv][e * 4 + head];
        float4 raw = *(const float4*)&h1[(size_t)s * 256 + li * 8];
        __half2* hp = (__half2*)&raw;
#pragma unroll
        for (int q = 0; q < 4; ++q) {
            float2 f = __half22float2(hp[q]);
            acc[q * 2]     = fmaf(a, f.x, acc[q * 2]);
            acc[q * 2 + 1] = fmaf(a, f.y, acc[q * 2 + 1]);
        }
    };
    auto gather = [&](int cnt) {
        int i = 0;
        for (; i + 7 < cnt; i += 8) {       // 8 edges: 4 per subgroup, 4 loads in flight/lane
            gath1(i + g); gath1(i + 2 + g); gath1(i + 4 + g); gath1(i + 6 + g);
        }
        for (; i + 1 < cnt; i += 2) gath1(i + g);
        if (i < cnt && g == 0) gath1(i);
    };

    if (deg <= 64) {
        float4 l = make_float4(-3e38f, -3e38f, -3e38f, -3e38f);
        if (lane < deg) {
            int s = esrc[e0 + lane];
            ss[wv][lane] = s;
            float4 as = *(const float4*)&asrc[(size_t)s * 4];
            l.x = lrelu(as.x + ad.x); l.y = lrelu(as.y + ad.y);
            l.z = lrelu(as.z + ad.z); l.w = lrelu(as.w + ad.w);
        }
        float4 m = l;
#pragma unroll
        for (int off = 1; off < 64; off <<= 1) {
            m.x = fmaxf(m.x, __shfl_xor(m.x, off));
            m.y = fmaxf(m.y, __shfl_xor(m.y, off));
            m.z = fmaxf(m.z, __shfl_xor(m.z, off));
            m.w = fmaxf(m.w, __shfl_xor(m.w, off));
        }
        float4 a = make_float4(0.f, 0.f, 0.f, 0.f);
        if (lane < deg) {
            a.x = __expf(l.x - m.x); a.y = __expf(l.y - m.y);
            a.z = __expf(l.z - m.z); a.w = __expf(l.w - m.w);
            *(float4*)&sa[wv][lane * 4] = a;
        }
        asum = a;
        gather(deg);
    } else {
        float4 m = make_float4(-3e38f, -3e38f, -3e38f, -3e38f);
        for (int p0 = e0; p0 < e1; p0 += 64) {
            int e = p0 + lane;
            if (e < e1) {
                int s = esrc[e];
                float4 as = *(const float4*)&asrc[(size_t)s * 4];
                m.x = fmaxf(m.x, lrelu(as.x + ad.x));
                m.y = fmaxf(m.y, lrelu(as.y + ad.y));
                m.z = fmaxf(m.z, lrelu(as.z + ad.z));
                m.w = fmaxf(m.w, lrelu(as.w + ad.w));
            }
        }
#pragma unroll
        for (int off = 1; off < 64; off <<= 1) {
            m.x = fmaxf(m.x, __shfl_xor(m.x, off));
            m.y = fmaxf(m.y, __shfl_xor(m.y, off));
            m.z = fmaxf(m.z, __shfl_xor(m.z, off));
            m.w = fmaxf(m.w, __shfl_xor(m.w, off));
        }
        for (int p0 = e0; p0 < e1; p0 += 64) {
            int cnt = min(64, e1 - p0);
            if (lane < cnt) {
                int s = esrc[p0 + lane];
                ss[wv][lane] = s;
                float4 as = *(const float4*)&asrc[(size_t)s * 4];
                float4 a;
                a.x = __expf(lrelu(as.x + ad.x) - m.x);
                a.y = __expf(lrelu(as.y + ad.y) - m.y);
                a.z = __expf(lrelu(as.z + ad.z) - m.z);
                a.w = __expf(lrelu(as.w + ad.w) - m.w);
                *(float4*)&sa[wv][lane * 4] = a;
                asum.x += a.x; asum.y += a.y; asum.z += a.z; asum.w += a.w;
            }
            gather(cnt);
        }
    }

    // cross-subgroup accumulator reduce
#pragma unroll
    for (int q = 0; q < 8; ++q) acc[q] += __shfl_xor(acc[q], 32);
    // alpha-sum reduce (full wave)
#pragma unroll
    for (int off = 1; off < 64; off <<= 1) {
        asum.x += __shfl_xor(asum.x, off);
        asum.y += __shfl_xor(asum.y, off);
        asum.z += __shfl_xor(asum.z, off);
        asum.w += __shfl_xor(asum.w, off);
    }
    if (g == 0) {
        float ssum = (head == 0) ? asum.x : (head == 1) ? asum.y : (head == 2) ? asum.z : asum.w;
        float inv = 1.f / (ssum + 1e-16f);
        float bb[8];
        *(float4*)&bb[0] = *(const float4*)&b1[li * 8];
        *(float4*)&bb[4] = *(const float4*)&b1[li * 8 + 4];
        half8 hv;
#pragma unroll
        for (int q = 0; q < 8; ++q) {
            float v = acc[q] * inv + bb[q];
            v = (v > 0.f) ? v : (__expf(v) - 1.f);
            hv[q] = (_Float16)v;
        }
        *(half8*)&y1[(size_t)n * 256 + li * 8] = hv;
    }
}

// ---------------- GEMM2 (MFMA fp16): h2 = y1 @ W2, fused att dots ----------------

__global__ __launch_bounds__(256, 3) void k_gemm2(const __half* __restrict__ y1,
                                                  const __half* __restrict__ W2t,
                                                  const float* __restrict__ att_src,
                                                  const float* __restrict__ att_dst,
                                                  __half* __restrict__ h2,
                                                  float* __restrict__ a_s,
                                                  float* __restrict__ a_d, int M) {
    __shared__ __align__(16) __half Ys[64 * 256];
    __shared__ __align__(16) __half Ws[32 * 256];
    const int tid = threadIdx.x;
    const int row0 = blockIdx.x * 64;

    for (int t = 0; t < 8; ++t) {
        int c = tid + t * 256;
        int row = c >> 5, ch = c & 31;
        int r = row0 + row;
        float4 v = make_float4(0.f, 0.f, 0.f, 0.f);
        if (r < M) v = *(const float4*)&y1[(size_t)r * 256 + ch * 8];
        *(float4*)((char*)Ys + row * 512 + ((ch * 16) ^ ((row & 7) << 4))) = v;
    }
    for (int t = 0; t < 4; ++t) {
        int c = tid + t * 256;
        int n = c >> 5, ch = c & 31;
        int p = ((n & 1) << 4) | (n >> 1);
        float4 v = *(const float4*)&W2t[(size_t)n * 256 + ch * 8];
        *(float4*)((char*)Ws + p * 512 + ((ch * 16) ^ ((p & 7) << 4))) = v;
    }
    __syncthreads();

    const int w = tid >> 6, lane = tid & 63;
    const int col_l = lane & 15, kgrp = lane >> 4;
    const int arow = w * 16 + col_l;
    const int sw = (col_l & 7) << 4;

    f32x4 acc[2];
    acc[0] = (f32x4){0.f, 0.f, 0.f, 0.f};
    acc[1] = (f32x4){0.f, 0.f, 0.f, 0.f};

#pragma unroll
    for (int ks = 0; ks < 8; ++ks) {
        int kchunk = (ks * 4 + kgrp) * 16;
        half8 av = *(const half8*)((const char*)Ys + arow * 512 + (kchunk ^ sw));
#pragma unroll
        for (int nt = 0; nt < 2; ++nt) {
            half8 bv = *(const half8*)((const char*)Ws + (nt * 16 + col_l) * 512 + (kchunk ^ sw));
            acc[nt] = __builtin_amdgcn_mfma_f32_16x16x32_f16(av, bv, acc[nt], 0, 0, 0);
        }
    }

    float asv[2], adv[2];
    asv[0] = att_src[col_l * 2]; asv[1] = att_src[col_l * 2 + 1];
    adv[0] = att_dst[col_l * 2]; adv[1] = att_dst[col_l * 2 + 1];
    const int rbase = row0 + w * 16 + kgrp * 4;
#pragma unroll
    for (int reg = 0; reg < 4; ++reg) {
        int gr = rbase + reg;
        if (gr < M) {
            __half2 hv = __floats2half2_rn(acc[0][reg], acc[1][reg]);
            *(__half2*)&h2[(size_t)gr * 32 + col_l * 2] = hv;
        }
        float s_ = fmaf(acc[0][reg], asv[0], acc[1][reg] * asv[1]);
        float d_ = fmaf(acc[0][reg], adv[0], acc[1][reg] * adv[1]);
#pragma unroll
        for (int off = 1; off < 16; off <<= 1) {
            s_ += __shfl_xor(s_, off);
            d_ += __shfl_xor(d_, off);
        }
        if (col_l == 0 && gr < M) { a_s[gr] = s_; a_d[gr] = d_; }
    }
}

// ---------------- agg layer 2 (fused softmax): wave-per-node ----------------

__global__ __launch_bounds__(256) void k_agg2(const __half* __restrict__ h2,
                                              const int* __restrict__ row_ptr,
                                              const int* __restrict__ esrc,
                                              const float* __restrict__ asrc,
                                              const float* __restrict__ adst,
                                              const float* __restrict__ b2,
                                              float* __restrict__ out, int N) {
    __shared__ int ss[4][64];
    __shared__ float sa[4][64];
    int tid = threadIdx.x;
    int wv = tid >> 6, lane = tid & 63;
    int n = blockIdx.x * 4 + wv;
    if (n >= N) return;
    int grp = lane >> 4, cl = lane & 15;
    int e0 = row_ptr[n], e1 = row_ptr[n + 1];
    int deg = e1 - e0;
    float ad = adst[n];
    float2 acc = make_float2(0.f, 0.f);
    float asum = 0.f;

    auto gather = [&](int cnt) {
        int i = 0;
        for (; i + 7 < cnt; i += 8) {
            int ea = i + grp, eb = i + 4 + grp;
            int s0 = ss[wv][ea], s1 = ss[wv][eb];
            float a0 = sa[wv][ea], a1 = sa[wv][eb];
            __half2 v0 = *(const __half2*)&h2[(size_t)s0 * 32 + cl * 2];
            __half2 v1 = *(const __half2*)&h2[(size_t)s1 * 32 + cl * 2];
            float2 f0 = __half22float2(v0), f1 = __half22float2(v1);
            acc.x = fmaf(a0, f0.x, acc.x); acc.y = fmaf(a0, f0.y, acc.y);
            acc.x = fmaf(a1, f1.x, acc.x); acc.y = fmaf(a1, f1.y, acc.y);
        }
        for (; i < cnt; i += 4) {
            int e = i + grp;
            if (e < cnt) {
                int s0 = ss[wv][e];
                float a0 = sa[wv][e];
                __half2 v0 = *(const __half2*)&h2[(size_t)s0 * 32 + cl * 2];
                float2 f0 = __half22float2(v0);
                acc.x = fmaf(a0, f0.x, acc.x); acc.y = fmaf(a0, f0.y, acc.y);
            }
        }
    };

    if (deg <= 64) {
        float l = -3e38f;
        if (lane < deg) {
            int s = esrc[e0 + lane];
            ss[wv][lane] = s;
            l = lrelu(asrc[s] + ad);
        }
        float m = l;
#pragma unroll
        for (int off = 1; off < 64; off <<= 1) m = fmaxf(m, __shfl_xor(m, off));
        float a = 0.f;
        if (lane < deg) {
            a = __expf(l - m);
            sa[wv][lane] = a;
        }
        asum = a;
        gather(deg);
    } else {
        float m = -3e38f;
        for (int p0 = e0; p0 < e1; p0 += 64) {
            int e = p0 + lane;
            if (e < e1) m = fmaxf(m, lrelu(asrc[esrc[e]] + ad));
        }
#pragma unroll
        for (int off = 1; off < 64; off <<= 1) m = fmaxf(m, __shfl_xor(m, off));
        for (int p0 = e0; p0 < e1; p0 += 64) {
            int cnt = min(64, e1 - p0);
            if (lane < cnt) {
                int s = esrc[p0 + lane];
                ss[wv][lane] = s;
                float a = __expf(lrelu(asrc[s] + ad) - m);
                sa[wv][lane] = a;
                asum += a;
            }
            gather(cnt);
        }
    }

    acc.x += __shfl_xor(acc.x, 16); acc.y += __shfl_xor(acc.y, 16);
    acc.x += __shfl_xor(acc.x, 32); acc.y += __shfl_xor(acc.y, 32);
#pragma unroll
    for (int off = 1; off < 64; off <<= 1) asum += __shfl_xor(asum, off);
    if (grp == 0) {
        float inv = 1.f / (asum + 1e-16f);
        float2 o;
        o.x = acc.x * inv + b2[cl * 2];
        o.y = acc.y * inv + b2[cl * 2 + 1];
        *(float2*)&out[(size_t)n * 32 + cl * 2] = o;
    }
}

// ---------------- launcher ----------------

extern "C" void kernel_launch(void* const* d_in, const int* in_sizes, int n_in,
                              void* d_out, int out_size, void* d_ws, size_t ws_size,
                              hipStream_t stream) {
    const float* x   = (const float*)d_in[0];
    const int*   ei  = (const int*)d_in[1];
    const float* W1  = (const float*)d_in[2];
    const float* as1 = (const float*)d_in[3];
    const float* ad1 = (const float*)d_in[4];
    const float* b1  = (const float*)d_in[5];
    const float* W2  = (const float*)d_in[6];
    const float* as2 = (const float*)d_in[7];
    const float* ad2 = (const float*)d_in[8];
    const float* b2  = (const float*)d_in[9];
    float* out = (float*)d_out;

    const int N = in_sizes[0] / 128;   // 50000
    const int E = in_sizes[1] / 2;     // 800000
    const int* src = ei;
    const int* dstp = ei + E;
    const int nb = (N + 1023) / 1024;

    char* ws = (char*)d_ws;
    size_t off = 0;
    auto alloc = [&](size_t nbytes) {
        void* p = ws + off;
        off += (nbytes + 255) & ~(size_t)255;
        return p;
    };
    int* counts    = (int*)alloc((size_t)N * 4);
    int* row_ptr   = (int*)alloc((size_t)(N + 1) * 4);
    int* row_fill  = (int*)alloc((size_t)N * 4);
    int* esrc      = (int*)alloc((size_t)E * 4);
    __half* h1     = (__half*)alloc((size_t)N * 256 * 2);
    __half* y1     = (__half*)alloc((size_t)N * 256 * 2);
    __half* h2     = (__half*)alloc((size_t)N * 32 * 2);
    float* a_s1    = (float*)alloc((size_t)N * 4 * 4);
    float* a_d1    = (float*)alloc((size_t)N * 4 * 4);
    float* a_s2    = (float*)alloc((size_t)N * 4);
    float* a_d2    = (float*)alloc((size_t)N * 4);
    int* bsum      = (int*)alloc((size_t)nb * 4);
    int* boff      = (int*)alloc((size_t)nb * 4);
    __half* Wt     = (__half*)alloc((size_t)256 * 128 * 2);
    __half* W2t    = (__half*)alloc((size_t)32 * 256 * 2);

    hipMemsetAsync(counts, 0, (size_t)N * 4, stream);
    k_hist<<<(E + 255) / 256, 256, 0, stream>>>(dstp, counts, E);
    k_scan1<<<nb, 256, 0, stream>>>(counts, bsum, N);
    k_scan2<<<1, 64, 0, stream>>>(bsum, boff, &row_ptr[N], nb);
    k_scan3<<<nb, 256, 0, stream>>>(counts, boff, row_ptr, row_fill, N);
    k_scatter<<<(E + 255) / 256, 256, 0, stream>>>(src, dstp, row_fill, esrc, E);

    k_wt<<<288, 256, 0, stream>>>(W1, W2, Wt, W2t);

    k_gemm1<<<dim3((N + 127) / 128, 2), 256, 0, stream>>>(x, Wt, as1, ad1, h1, a_s1, a_d1, N);
    k_agg1<<<(N + 3) / 4, 256, 0, stream>>>(h1, row_ptr, esrc, a_s1, a_d1, b1, y1, N);

    k_gemm2<<<(N + 63) / 64, 256, 0, stream>>>(y1, W2t, as2, ad2, h2, a_s2, a_d2, N);
    k_agg2<<<(N + 3) / 4, 256, 0, stream>>>(h2, row_ptr, esrc, a_s2, a_d2, b2, out, N);
}

// Round 14
// 214.399 us; speedup vs baseline: 3.3310x; 1.0369x over previous
//
#include <hip/hip_runtime.h>
#include <hip/hip_bf16.h>
#include <hip/hip_fp16.h>

#define NEG_SLOPE 0.2f

typedef _Float16 half8 __attribute__((ext_vector_type(8)));
typedef float f32x4 __attribute__((ext_vector_type(4)));

__device__ __forceinline__ float lrelu(float x) { return x >= 0.f ? x : NEG_SLOPE * x; }

__device__ __forceinline__ float4 h4_to_f4(float2 r) {
    __half2 a = *(__half2*)&r.x;
    __half2 b = *(__half2*)&r.y;
    float2 fa = __half22float2(a), fb = __half22float2(b);
    return make_float4(fa.x, fa.y, fb.x, fb.y);
}

__device__ __forceinline__ void fma4(float a, float4 v, float4& acc) {
    acc.x = fmaf(a, v.x, acc.x); acc.y = fmaf(a, v.y, acc.y);
    acc.z = fmaf(a, v.z, acc.z); acc.w = fmaf(a, v.w, acc.w);
}

// ---------------- CSR construction ----------------

__global__ void k_hist(const int* __restrict__ dst, int* __restrict__ counts, int E) {
    int e = blockIdx.x * 256 + threadIdx.x;
    if (e < E) atomicAdd(&counts[dst[e]], 1);
}

__global__ __launch_bounds__(256) void k_scan1(const int* __restrict__ counts,
                                               int* __restrict__ bsum, int N) {
    __shared__ int wsum[4];
    int b = blockIdx.x, t = threadIdx.x;
    int i0 = b * 1024 + t * 4;
    int s = 0;
    if (i0 < N) { int4 v = *(const int4*)&counts[i0]; s = v.x + v.y + v.z + v.w; }
#pragma unroll
    for (int off = 32; off; off >>= 1) s += __shfl_down(s, off);
    if ((t & 63) == 0) wsum[t >> 6] = s;
    __syncthreads();
    if (t == 0) bsum[b] = wsum[0] + wsum[1] + wsum[2] + wsum[3];
}

__global__ void k_scan2(const int* __restrict__ bsum, int* __restrict__ boff,
                        int* __restrict__ row_ptrN, int nb) {
    int t = threadIdx.x;  // 64 threads, nb <= 64
    int v = (t < nb) ? bsum[t] : 0;
    int incl = v;
#pragma unroll
    for (int off = 1; off < 64; off <<= 1) {
        int u = __shfl_up(incl, off);
        if (t >= off) incl += u;
    }
    if (t < nb) boff[t] = incl - v;
    if (t == nb - 1) *row_ptrN = incl;
}

__global__ __launch_bounds__(256) void k_scan3(const int* __restrict__ counts,
                                               const int* __restrict__ boff,
                                               int* __restrict__ row_ptr,
                                               int* __restrict__ row_fill, int N) {
    __shared__ int lds[256];
    int b = blockIdx.x, t = threadIdx.x;
    int i0 = b * 1024 + t * 4;
    int4 v = make_int4(0, 0, 0, 0);
    if (i0 < N) v = *(const int4*)&counts[i0];
    int tot = v.x + v.y + v.z + v.w;
    lds[t] = tot;
    __syncthreads();
    for (int off = 1; off < 256; off <<= 1) {
        int u = (t >= off) ? lds[t - off] : 0;
        __syncthreads();
        lds[t] += u;
        __syncthreads();
    }
    int excl = lds[t] - tot;
    int run = boff[b] + excl;
    if (i0 < N) {
        row_ptr[i0] = run;     row_fill[i0] = run;     run += v.x;
        row_ptr[i0 + 1] = run; row_fill[i0 + 1] = run; run += v.y;
        row_ptr[i0 + 2] = run; row_fill[i0 + 2] = run; run += v.z;
        row_ptr[i0 + 3] = run; row_fill[i0 + 3] = run;
    }
}

__global__ void k_scatter(const int* __restrict__ src, const int* __restrict__ dst,
                          int* __restrict__ row_fill, int* __restrict__ esrc, int E) {
    int e = blockIdx.x * 256 + threadIdx.x;
    if (e < E) {
        int p = atomicAdd(&row_fill[dst[e]], 1);
        esrc[p] = src[e];
    }
}

// ---------------- weight transposes to fp16 (merged) ----------------

__global__ __launch_bounds__(256) void k_wt(const float* __restrict__ W1,
                                            const float* __restrict__ W2,
                                            __half* __restrict__ W1t,
                                            __half* __restrict__ W2t) {
    int b = blockIdx.x, k = threadIdx.x;
    if (b < 256) {
        if (k < 128) W1t[b * 128 + k] = __float2half(W1[(size_t)k * 256 + b]);
    } else {
        int n = b - 256;   // 0..31
        W2t[n * 256 + k] = __float2half(W2[(size_t)k * 32 + n]);
    }
}

// ---------------- GEMM1 (MFMA fp16): h1 = x @ W1, fused att dots ----------------

__global__ __launch_bounds__(256, 2) void k_gemm1(const float* __restrict__ x,
                                                  const __half* __restrict__ Wt,
                                                  const float* __restrict__ att_src,
                                                  const float* __restrict__ att_dst,
                                                  __half* __restrict__ h,
                                                  float* __restrict__ a_s,
                                                  float* __restrict__ a_d, int M) {
    __shared__ __align__(16) __half Xs[128 * 128];   // [row][k], XOR-swizzled 16B chunks
    __shared__ __align__(16) __half Ws[128 * 128];   // [perm-slot][k], XOR-swizzled
    const int tid = threadIdx.x;
    const int row0 = blockIdx.x * 128;
    const int by = blockIdx.y;
    const int col0 = by * 128;

    for (int t = 0; t < 8; ++t) {
        int c = tid + t * 256;
        int row = c >> 4, ch = c & 15;
        int r = row0 + row;
        float4 va = make_float4(0.f, 0.f, 0.f, 0.f), vb = va;
        if (r < M) {
            va = *(const float4*)&x[(size_t)r * 128 + ch * 8];
            vb = *(const float4*)&x[(size_t)r * 128 + ch * 8 + 4];
        }
        half8 hv;
        hv[0] = (_Float16)va.x; hv[1] = (_Float16)va.y;
        hv[2] = (_Float16)va.z; hv[3] = (_Float16)va.w;
        hv[4] = (_Float16)vb.x; hv[5] = (_Float16)vb.y;
        hv[6] = (_Float16)vb.z; hv[7] = (_Float16)vb.w;
        *(half8*)((char*)Xs + row * 256 + ((ch * 16) ^ ((row & 7) << 4))) = hv;
    }
    for (int t = 0; t < 8; ++t) {
        int c = tid + t * 256;
        int n = c >> 4, ch = c & 15;
        int p = ((n & 7) << 4) | (n >> 3);
        float4 v = *(const float4*)&Wt[(size_t)(col0 + n) * 128 + ch * 8];
        *(float4*)((char*)Ws + p * 256 + ((ch * 16) ^ ((p & 7) << 4))) = v;
    }
    __syncthreads();

    const int w = tid >> 6, lane = tid & 63;
    const int col_l = lane & 15, kgrp = lane >> 4;
    const int sw = (col_l & 7) << 4;
    const int arow0 = w * 32 + col_l;
    const int arow1 = arow0 + 16;

    f32x4 acc[2][8];
#pragma unroll
    for (int mt = 0; mt < 2; ++mt)
#pragma unroll
        for (int nt = 0; nt < 8; ++nt) acc[mt][nt] = (f32x4){0.f, 0.f, 0.f, 0.f};

#pragma unroll
    for (int ks = 0; ks < 4; ++ks) {
        int kchunk = (ks * 4 + kgrp) * 16;
        half8 av0 = *(const half8*)((const char*)Xs + arow0 * 256 + (kchunk ^ sw));
        half8 av1 = *(const half8*)((const char*)Xs + arow1 * 256 + (kchunk ^ sw));
#pragma unroll
        for (int nt = 0; nt < 8; ++nt) {
            half8 bv = *(const half8*)((const char*)Ws + (nt * 16 + col_l) * 256 + (kchunk ^ sw));
            acc[0][nt] = __builtin_amdgcn_mfma_f32_16x16x32_f16(av0, bv, acc[0][nt], 0, 0, 0);
            acc[1][nt] = __builtin_amdgcn_mfma_f32_16x16x32_f16(av1, bv, acc[1][nt], 0, 0, 0);
        }
    }

    float asv[8], adv[8];
    *(float4*)&asv[0] = *(const float4*)&att_src[col0 + col_l * 8];
    *(float4*)&asv[4] = *(const float4*)&att_src[col0 + col_l * 8 + 4];
    *(float4*)&adv[0] = *(const float4*)&att_dst[col0 + col_l * 8];
    *(float4*)&adv[4] = *(const float4*)&att_dst[col0 + col_l * 8 + 4];

#pragma unroll
    for (int mt = 0; mt < 2; ++mt) {
        const int rbase = row0 + w * 32 + mt * 16 + kgrp * 4;
#pragma unroll
        for (int reg = 0; reg < 4; ++reg) {
            int gr = rbase + reg;
            if (gr < M) {
                half8 hv;
#pragma unroll
                for (int nt = 0; nt < 8; ++nt) hv[nt] = (_Float16)acc[mt][nt][reg];
                *(half8*)&h[(size_t)gr * 256 + col0 + col_l * 8] = hv;
            }
            float s_ = 0.f, d_ = 0.f;
#pragma unroll
            for (int nt = 0; nt < 8; ++nt) {
                s_ = fmaf(acc[mt][nt][reg], asv[nt], s_);
                d_ = fmaf(acc[mt][nt][reg], adv[nt], d_);
            }
#pragma unroll
            for (int off = 1; off < 8; off <<= 1) {
                s_ += __shfl_xor(s_, off);
                d_ += __shfl_xor(d_, off);
            }
            if ((col_l & 7) == 0 && gr < M) {
                int head = by * 2 + (col_l >> 3);
                a_s[(size_t)gr * 4 + head] = s_;
                a_d[(size_t)gr * 4 + head] = d_;
            }
        }
    }
}

// ---------------- agg layer 1 (fused softmax): wave-per-node ----------------

__global__ __launch_bounds__(256) void k_agg1(const __half* __restrict__ h1,
                                              const int* __restrict__ row_ptr,
                                              const int* __restrict__ esrc,
                                              const float* __restrict__ asrc,
                                              const float* __restrict__ adst,
                                              const float* __restrict__ b1,
                                              __half* __restrict__ y1, int N) {
    __shared__ int ss[4][64];
    __shared__ float sa[4][64 * 4];
    int tid = threadIdx.x;
    int wv = tid >> 6, lane = tid & 63;
    int n = blockIdx.x * 4 + wv;
    if (n >= N) return;
    int head = lane >> 4;
    int e0 = row_ptr[n], e1 = row_ptr[n + 1];
    int deg = e1 - e0;
    const float4 ad = *(const float4*)&adst[(size_t)n * 4];
    float4 acc = make_float4(0.f, 0.f, 0.f, 0.f);
    float4 asum = make_float4(0.f, 0.f, 0.f, 0.f);

    if (deg <= 64) {
        float4 l = make_float4(-3e38f, -3e38f, -3e38f, -3e38f);
        if (lane < deg) {
            int s = esrc[e0 + lane];
            ss[wv][lane] = s;
            float4 as = *(const float4*)&asrc[(size_t)s * 4];
            l.x = lrelu(as.x + ad.x); l.y = lrelu(as.y + ad.y);
            l.z = lrelu(as.z + ad.z); l.w = lrelu(as.w + ad.w);
        }
        float4 m = l;
#pragma unroll
        for (int off = 1; off < 64; off <<= 1) {
            m.x = fmaxf(m.x, __shfl_xor(m.x, off));
            m.y = fmaxf(m.y, __shfl_xor(m.y, off));
            m.z = fmaxf(m.z, __shfl_xor(m.z, off));
            m.w = fmaxf(m.w, __shfl_xor(m.w, off));
        }
        float4 a = make_float4(0.f, 0.f, 0.f, 0.f);
        if (lane < deg) {
            a.x = __expf(l.x - m.x); a.y = __expf(l.y - m.y);
            a.z = __expf(l.z - m.z); a.w = __expf(l.w - m.w);
            *(float4*)&sa[wv][lane * 4] = a;
        }
        asum = a;
        int i = 0;
        for (; i + 3 < deg; i += 4) {
            int s0 = ss[wv][i], s1 = ss[wv][i + 1], s2 = ss[wv][i + 2], s3 = ss[wv][i + 3];
            float a0 = sa[wv][i * 4 + head],       a1 = sa[wv][(i + 1) * 4 + head];
            float a2 = sa[wv][(i + 2) * 4 + head], a3 = sa[wv][(i + 3) * 4 + head];
            float2 r0 = *(const float2*)&h1[(size_t)s0 * 256 + lane * 4];
            float2 r1 = *(const float2*)&h1[(size_t)s1 * 256 + lane * 4];
            float2 r2 = *(const float2*)&h1[(size_t)s2 * 256 + lane * 4];
            float2 r3 = *(const float2*)&h1[(size_t)s3 * 256 + lane * 4];
            fma4(a0, h4_to_f4(r0), acc);
            fma4(a1, h4_to_f4(r1), acc);
            fma4(a2, h4_to_f4(r2), acc);
            fma4(a3, h4_to_f4(r3), acc);
        }
        for (; i < deg; ++i) {
            int s0 = ss[wv][i];
            float a0 = sa[wv][i * 4 + head];
            float2 r0 = *(const float2*)&h1[(size_t)s0 * 256 + lane * 4];
            fma4(a0, h4_to_f4(r0), acc);
        }
    } else {
        float4 m = make_float4(-3e38f, -3e38f, -3e38f, -3e38f);
        for (int p0 = e0; p0 < e1; p0 += 64) {
            int e = p0 + lane;
            if (e < e1) {
                int s = esrc[e];
                float4 as = *(const float4*)&asrc[(size_t)s * 4];
                m.x = fmaxf(m.x, lrelu(as.x + ad.x));
                m.y = fmaxf(m.y, lrelu(as.y + ad.y));
                m.z = fmaxf(m.z, lrelu(as.z + ad.z));
                m.w = fmaxf(m.w, lrelu(as.w + ad.w));
            }
        }
#pragma unroll
        for (int off = 1; off < 64; off <<= 1) {
            m.x = fmaxf(m.x, __shfl_xor(m.x, off));
            m.y = fmaxf(m.y, __shfl_xor(m.y, off));
            m.z = fmaxf(m.z, __shfl_xor(m.z, off));
            m.w = fmaxf(m.w, __shfl_xor(m.w, off));
        }
        for (int p0 = e0; p0 < e1; p0 += 64) {
            int cnt = min(64, e1 - p0);
            if (lane < cnt) {
                int s = esrc[p0 + lane];
                ss[wv][lane] = s;
                float4 as = *(const float4*)&asrc[(size_t)s * 4];
                float4 a;
                a.x = __expf(lrelu(as.x + ad.x) - m.x);
                a.y = __expf(lrelu(as.y + ad.y) - m.y);
                a.z = __expf(lrelu(as.z + ad.z) - m.z);
                a.w = __expf(lrelu(as.w + ad.w) - m.w);
                *(float4*)&sa[wv][lane * 4] = a;
                asum.x += a.x; asum.y += a.y; asum.z += a.z; asum.w += a.w;
            }
            int i = 0;
            for (; i + 3 < cnt; i += 4) {
                int s0 = ss[wv][i], s1 = ss[wv][i + 1], s2 = ss[wv][i + 2], s3 = ss[wv][i + 3];
                float a0 = sa[wv][i * 4 + head],       a1 = sa[wv][(i + 1) * 4 + head];
                float a2 = sa[wv][(i + 2) * 4 + head], a3 = sa[wv][(i + 3) * 4 + head];
                float2 r0 = *(const float2*)&h1[(size_t)s0 * 256 + lane * 4];
                float2 r1 = *(const float2*)&h1[(size_t)s1 * 256 + lane * 4];
                float2 r2 = *(const float2*)&h1[(size_t)s2 * 256 + lane * 4];
                float2 r3 = *(const float2*)&h1[(size_t)s3 * 256 + lane * 4];
                fma4(a0, h4_to_f4(r0), acc);
                fma4(a1, h4_to_f4(r1), acc);
                fma4(a2, h4_to_f4(r2), acc);
                fma4(a3, h4_to_f4(r3), acc);
            }
            for (; i < cnt; ++i) {
                int s0 = ss[wv][i];
                float a0 = sa[wv][i * 4 + head];
                float2 r0 = *(const float2*)&h1[(size_t)s0 * 256 + lane * 4];
                fma4(a0, h4_to_f4(r0), acc);
            }
        }
    }

#pragma unroll
    for (int off = 1; off < 64; off <<= 1) {
        asum.x += __shfl_xor(asum.x, off);
        asum.y += __shfl_xor(asum.y, off);
        asum.z += __shfl_xor(asum.z, off);
        asum.w += __shfl_xor(asum.w, off);
    }
    float ssum = (head == 0) ? asum.x : (head == 1) ? asum.y : (head == 2) ? asum.z : asum.w;
    float inv = 1.f / (ssum + 1e-16f);
    float4 bb = *(const float4*)&b1[lane * 4];
    float4 v;
    v.x = acc.x * inv + bb.x; v.y = acc.y * inv + bb.y;
    v.z = acc.z * inv + bb.z; v.w = acc.w * inv + bb.w;
    v.x = (v.x > 0.f) ? v.x : (__expf(v.x) - 1.f);
    v.y = (v.y > 0.f) ? v.y : (__expf(v.y) - 1.f);
    v.z = (v.z > 0.f) ? v.z : (__expf(v.z) - 1.f);
    v.w = (v.w > 0.f) ? v.w : (__expf(v.w) - 1.f);
    __half2 h01 = __floats2half2_rn(v.x, v.y);
    __half2 h23 = __floats2half2_rn(v.z, v.w);
    float2 st;
    *(__half2*)&st.x = h01;
    *(__half2*)&st.y = h23;
    *(float2*)&y1[(size_t)n * 256 + lane * 4] = st;
}

// ---------------- GEMM2 (MFMA fp16): h2 = y1 @ W2, fused att dots ----------------

__global__ __launch_bounds__(256, 3) void k_gemm2(const __half* __restrict__ y1,
                                                  const __half* __restrict__ W2t,
                                                  const float* __restrict__ att_src,
                                                  const float* __restrict__ att_dst,
                                                  __half* __restrict__ h2,
                                                  float* __restrict__ a_s,
                                                  float* __restrict__ a_d, int M) {
    __shared__ __align__(16) __half Ys[64 * 256];
    __shared__ __align__(16) __half Ws[32 * 256];
    const int tid = threadIdx.x;
    const int row0 = blockIdx.x * 64;

    for (int t = 0; t < 8; ++t) {
        int c = tid + t * 256;
        int row = c >> 5, ch = c & 31;
        int r = row0 + row;
        float4 v = make_float4(0.f, 0.f, 0.f, 0.f);
        if (r < M) v = *(const float4*)&y1[(size_t)r * 256 + ch * 8];
        *(float4*)((char*)Ys + row * 512 + ((ch * 16) ^ ((row & 7) << 4))) = v;
    }
    for (int t = 0; t < 4; ++t) {
        int c = tid + t * 256;
        int n = c >> 5, ch = c & 31;
        int p = ((n & 1) << 4) | (n >> 1);
        float4 v = *(const float4*)&W2t[(size_t)n * 256 + ch * 8];
        *(float4*)((char*)Ws + p * 512 + ((ch * 16) ^ ((p & 7) << 4))) = v;
    }
    __syncthreads();

    const int w = tid >> 6, lane = tid & 63;
    const int col_l = lane & 15, kgrp = lane >> 4;
    const int arow = w * 16 + col_l;
    const int sw = (col_l & 7) << 4;

    f32x4 acc[2];
    acc[0] = (f32x4){0.f, 0.f, 0.f, 0.f};
    acc[1] = (f32x4){0.f, 0.f, 0.f, 0.f};

#pragma unroll
    for (int ks = 0; ks < 8; ++ks) {
        int kchunk = (ks * 4 + kgrp) * 16;
        half8 av = *(const half8*)((const char*)Ys + arow * 512 + (kchunk ^ sw));
#pragma unroll
        for (int nt = 0; nt < 2; ++nt) {
            half8 bv = *(const half8*)((const char*)Ws + (nt * 16 + col_l) * 512 + (kchunk ^ sw));
            acc[nt] = __builtin_amdgcn_mfma_f32_16x16x32_f16(av, bv, acc[nt], 0, 0, 0);
        }
    }

    float asv[2], adv[2];
    asv[0] = att_src[col_l * 2]; asv[1] = att_src[col_l * 2 + 1];
    adv[0] = att_dst[col_l * 2]; adv[1] = att_dst[col_l * 2 + 1];
    const int rbase = row0 + w * 16 + kgrp * 4;
#pragma unroll
    for (int reg = 0; reg < 4; ++reg) {
        int gr = rbase + reg;
        if (gr < M) {
            __half2 hv = __floats2half2_rn(acc[0][reg], acc[1][reg]);
            *(__half2*)&h2[(size_t)gr * 32 + col_l * 2] = hv;
        }
        float s_ = fmaf(acc[0][reg], asv[0], acc[1][reg] * asv[1]);
        float d_ = fmaf(acc[0][reg], adv[0], acc[1][reg] * adv[1]);
#pragma unroll
        for (int off = 1; off < 16; off <<= 1) {
            s_ += __shfl_xor(s_, off);
            d_ += __shfl_xor(d_, off);
        }
        if (col_l == 0 && gr < M) { a_s[gr] = s_; a_d[gr] = d_; }
    }
}

// ---------------- agg layer 2 (fused softmax): wave-per-node ----------------

__global__ __launch_bounds__(256) void k_agg2(const __half* __restrict__ h2,
                                              const int* __restrict__ row_ptr,
                                              const int* __restrict__ esrc,
                                              const float* __restrict__ asrc,
                                              const float* __restrict__ adst,
                                              const float* __restrict__ b2,
                                              float* __restrict__ out, int N) {
    __shared__ int ss[4][64];
    __shared__ float sa[4][64];
    int tid = threadIdx.x;
    int wv = tid >> 6, lane = tid & 63;
    int n = blockIdx.x * 4 + wv;
    if (n >= N) return;
    int grp = lane >> 4, cl = lane & 15;
    int e0 = row_ptr[n], e1 = row_ptr[n + 1];
    int deg = e1 - e0;
    float ad = adst[n];
    float2 acc = make_float2(0.f, 0.f);
    float asum = 0.f;

    auto gather = [&](int cnt) {
        int i = 0;
        for (; i + 7 < cnt; i += 8) {
            int ea = i + grp, eb = i + 4 + grp;
            int s0 = ss[wv][ea], s1 = ss[wv][eb];
            float a0 = sa[wv][ea], a1 = sa[wv][eb];
            __half2 v0 = *(const __half2*)&h2[(size_t)s0 * 32 + cl * 2];
            __half2 v1 = *(const __half2*)&h2[(size_t)s1 * 32 + cl * 2];
            float2 f0 = __half22float2(v0), f1 = __half22float2(v1);
            acc.x = fmaf(a0, f0.x, acc.x); acc.y = fmaf(a0, f0.y, acc.y);
            acc.x = fmaf(a1, f1.x, acc.x); acc.y = fmaf(a1, f1.y, acc.y);
        }
        for (; i < cnt; i += 4) {
            int e = i + grp;
            if (e < cnt) {
                int s0 = ss[wv][e];
                float a0 = sa[wv][e];
                __half2 v0 = *(const __half2*)&h2[(size_t)s0 * 32 + cl * 2];
                float2 f0 = __half22float2(v0);
                acc.x = fmaf(a0, f0.x, acc.x); acc.y = fmaf(a0, f0.y, acc.y);
            }
        }
    };

    if (deg <= 64) {
        float l = -3e38f;
        if (lane < deg) {
            int s = esrc[e0 + lane];
            ss[wv][lane] = s;
            l = lrelu(asrc[s] + ad);
        }
        float m = l;
#pragma unroll
        for (int off = 1; off < 64; off <<= 1) m = fmaxf(m, __shfl_xor(m, off));
        float a = 0.f;
        if (lane < deg) {
            a = __expf(l - m);
            sa[wv][lane] = a;
        }
        asum = a;
        gather(deg);
    } else {
        float m = -3e38f;
        for (int p0 = e0; p0 < e1; p0 += 64) {
            int e = p0 + lane;
            if (e < e1) m = fmaxf(m, lrelu(asrc[esrc[e]] + ad));
        }
#pragma unroll
        for (int off = 1; off < 64; off <<= 1) m = fmaxf(m, __shfl_xor(m, off));
        for (int p0 = e0; p0 < e1; p0 += 64) {
            int cnt = min(64, e1 - p0);
            if (lane < cnt) {
                int s = esrc[p0 + lane];
                ss[wv][lane] = s;
                float a = __expf(lrelu(asrc[s] + ad) - m);
                sa[wv][lane] = a;
                asum += a;
            }
            gather(cnt);
        }
    }

    acc.x += __shfl_xor(acc.x, 16); acc.y += __shfl_xor(acc.y, 16);
    acc.x += __shfl_xor(acc.x, 32); acc.y += __shfl_xor(acc.y, 32);
#pragma unroll
    for (int off = 1; off < 64; off <<= 1) asum += __shfl_xor(asum, off);
    if (grp == 0) {
        float inv = 1.f / (asum + 1e-16f);
        float2 o;
        o.x = acc.x * inv + b2[cl * 2];
        o.y = acc.y * inv + b2[cl * 2 + 1];
        *(float2*)&out[(size_t)n * 32 + cl * 2] = o;
    }
}

// ---------------- launcher ----------------

extern "C" void kernel_launch(void* const* d_in, const int* in_sizes, int n_in,
                              void* d_out, int out_size, void* d_ws, size_t ws_size,
                              hipStream_t stream) {
    const float* x   = (const float*)d_in[0];
    const int*   ei  = (const int*)d_in[1];
    const float* W1  = (const float*)d_in[2];
    const float* as1 = (const float*)d_in[3];
    const float* ad1 = (const float*)d_in[4];
    const float* b1  = (const float*)d_in[5];
    const float* W2  = (const float*)d_in[6];
    const float* as2 = (const float*)d_in[7];
    const float* ad2 = (const float*)d_in[8];
    const float* b2  = (const float*)d_in[9];
    float* out = (float*)d_out;

    const int N = in_sizes[0] / 128;   // 50000
    const int E = in_sizes[1] / 2;     // 800000
    const int* src = ei;
    const int* dstp = ei + E;
    const int nb = (N + 1023) / 1024;

    char* ws = (char*)d_ws;
    size_t off = 0;
    auto alloc = [&](size_t nbytes) {
        void* p = ws + off;
        off += (nbytes + 255) & ~(size_t)255;
        return p;
    };
    int* counts    = (int*)alloc((size_t)N * 4);
    int* row_ptr   = (int*)alloc((size_t)(N + 1) * 4);
    int* row_fill  = (int*)alloc((size_t)N * 4);
    int* esrc      = (int*)alloc((size_t)E * 4);
    __half* h1     = (__half*)alloc((size_t)N * 256 * 2);
    __half* y1     = (__half*)alloc((size_t)N * 256 * 2);
    __half* h2     = (__half*)alloc((size_t)N * 32 * 2);
    float* a_s1    = (float*)alloc((size_t)N * 4 * 4);
    float* a_d1    = (float*)alloc((size_t)N * 4 * 4);
    float* a_s2    = (float*)alloc((size_t)N * 4);
    float* a_d2    = (float*)alloc((size_t)N * 4);
    int* bsum      = (int*)alloc((size_t)nb * 4);
    int* boff      = (int*)alloc((size_t)nb * 4);
    __half* Wt     = (__half*)alloc((size_t)256 * 128 * 2);
    __half* W2t    = (__half*)alloc((size_t)32 * 256 * 2);

    hipMemsetAsync(counts, 0, (size_t)N * 4, stream);
    k_hist<<<(E + 255) / 256, 256, 0, stream>>>(dstp, counts, E);
    k_scan1<<<nb, 256, 0, stream>>>(counts, bsum, N);
    k_scan2<<<1, 64, 0, stream>>>(bsum, boff, &row_ptr[N], nb);
    k_scan3<<<nb, 256, 0, stream>>>(counts, boff, row_ptr, row_fill, N);
    k_scatter<<<(E + 255) / 256, 256, 0, stream>>>(src, dstp, row_fill, esrc, E);

    k_wt<<<288, 256, 0, stream>>>(W1, W2, Wt, W2t);

    k_gemm1<<<dim3((N + 127) / 128, 2), 256, 0, stream>>>(x, Wt, as1, ad1, h1, a_s1, a_d1, N);
    k_agg1<<<(N + 3) / 4, 256, 0, stream>>>(h1, row_ptr, esrc, a_s1, a_d1, b1, y1, N);

    k_gemm2<<<(N + 63) / 64, 256, 0, stream>>>(y1, W2t, as2, ad2, h2, a_s2, a_d2, N);
    k_agg2<<<(N + 3) / 4, 256, 0, stream>>>(h2, row_ptr, esrc, a_s2, a_d2, b2, out, N);
}